// Round 2
// baseline (282.456 us; speedup 1.0000x reference)
//
#include <hip/hip_runtime.h>
#include <math.h>

#define NEG_INF -1e9f

// ---------------------------------------------------------------------------
// K1: energy[n,t] = dot(key[n,t,:], query[n,:]), masked to NEG_INF for t>=len.
// One wave per 8 rows. D == 256 == 64 lanes * float4.
// Writes energy into the attention slot of d_out (normalized in-place by K2).
// ---------------------------------------------------------------------------
__global__ __launch_bounds__(256) void energy_kernel(
    const float* __restrict__ query,   // (N, D)
    const float* __restrict__ key,     // (N, T, D)
    const int*   __restrict__ lens,    // (N,)
    float*       __restrict__ energy,  // (N, T)
    int N, int T)
{
    const int D = 256;
    const int ROWS_PER_WAVE = 8;
    int wave = (int)((blockIdx.x * blockDim.x + threadIdx.x) >> 6);
    int lane = threadIdx.x & 63;
    long long r0 = (long long)wave * ROWS_PER_WAVE;
    int n  = (int)(r0 / T);
    int t0 = (int)(r0 % T);
    if (n >= N) return;

    // query fragment: lane owns d = lane*4 .. lane*4+3
    const float4 q = *reinterpret_cast<const float4*>(query + (long long)n * D + lane * 4);
    const int len = lens[n];
    const float* krow = key + ((long long)n * T + t0) * D + lane * 4;
    float* erow = energy + (long long)n * T + t0;

    #pragma unroll
    for (int i = 0; i < ROWS_PER_WAVE; ++i) {
        const float4 k4 = *reinterpret_cast<const float4*>(krow + (long long)i * D);
        float p = k4.x * q.x + k4.y * q.y + k4.z * q.z + k4.w * q.w;
        #pragma unroll
        for (int off = 32; off >= 1; off >>= 1)
            p += __shfl_xor(p, off, 64);
        if (lane == 0) {
            int t = t0 + i;
            erow[i] = (t >= len) ? NEG_INF : p;
        }
    }
}

// ---------------------------------------------------------------------------
// K2: in-place row softmax over T=2048. One block (256 threads) per n.
// ---------------------------------------------------------------------------
__global__ __launch_bounds__(256) void softmax_kernel(
    float* __restrict__ att,  // (N, T): energy in, attention out
    int T)
{
    __shared__ float sred[256];
    const int n   = blockIdx.x;
    const int tid = threadIdx.x;
    float* row = att + (long long)n * T;

    float vals[8];
    float m = -INFINITY;
    #pragma unroll
    for (int i = 0; i < 8; ++i) {
        vals[i] = row[tid + (i << 8)];
        m = fmaxf(m, vals[i]);
    }
    sred[tid] = m;
    __syncthreads();
    #pragma unroll
    for (int s = 128; s >= 1; s >>= 1) {
        if (tid < s) sred[tid] = fmaxf(sred[tid], sred[tid + s]);
        __syncthreads();
    }
    m = sred[0];
    __syncthreads();

    float sum = 0.f;
    #pragma unroll
    for (int i = 0; i < 8; ++i) {
        vals[i] = __expf(vals[i] - m);
        sum += vals[i];
    }
    sred[tid] = sum;
    __syncthreads();
    #pragma unroll
    for (int s = 128; s >= 1; s >>= 1) {
        if (tid < s) sred[tid] += sred[tid + s];
        __syncthreads();
    }
    const float inv = 1.0f / sred[0];
    #pragma unroll
    for (int i = 0; i < 8; ++i)
        row[tid + (i << 8)] = vals[i] * inv;
}

// ---------------------------------------------------------------------------
// K3: context[n,v] = sum_t att[n,t] * value[n,t,v]. V == 256.
// Block = 256 threads (4 waves). Each wave handles 32 t-rows of a 128-row
// chunk; lane owns v4 = lane*4 (float4 -> one wave covers a full 1KB row).
// LDS-reduce the 4 waves, then one atomicAdd per v per block.
// ---------------------------------------------------------------------------
__global__ __launch_bounds__(256) void context_kernel(
    const float* __restrict__ att,     // (N, T)
    const float* __restrict__ value,   // (N, T, V)
    float*       __restrict__ context, // (N, V), pre-zeroed
    int T)
{
    const int V = 256;
    const int CHUNK = 128;
    __shared__ float red[4][256];

    const int n    = blockIdx.y;
    const int t0   = blockIdx.x * CHUNK;
    const int wid  = threadIdx.x >> 6;   // 0..3
    const int lane = threadIdx.x & 63;
    const int v4   = lane * 4;

    const float* arow = att + (long long)n * T;
    const float* vbase = value + ((long long)n * T + t0 + wid * 32) * V + v4;

    float4 acc = make_float4(0.f, 0.f, 0.f, 0.f);
    #pragma unroll 4
    for (int i = 0; i < 32; ++i) {
        const float a = arow[t0 + wid * 32 + i];
        const float4 val = *reinterpret_cast<const float4*>(vbase + (long long)i * V);
        acc.x += a * val.x;
        acc.y += a * val.y;
        acc.z += a * val.z;
        acc.w += a * val.w;
    }
    *reinterpret_cast<float4*>(&red[wid][v4]) = acc;
    __syncthreads();

    const int v = threadIdx.x;
    const float s = red[0][v] + red[1][v] + red[2][v] + red[3][v];
    atomicAdd(context + (long long)n * V + v, s);
}

// ---------------------------------------------------------------------------
extern "C" void kernel_launch(void* const* d_in, const int* in_sizes, int n_in,
                              void* d_out, int out_size, void* d_ws, size_t ws_size,
                              hipStream_t stream) {
    const float* query = (const float*)d_in[0];
    const float* key   = (const float*)d_in[1];
    const float* value = (const float*)d_in[2];
    const int*   lens  = (const int*)d_in[3];

    const int N = in_sizes[3];                 // 64
    const int D = in_sizes[0] / N;             // 256
    const int T = in_sizes[1] / (N * D);       // 2048
    const int V = in_sizes[2] / (N * T);       // 256
    (void)D; (void)V; (void)d_ws; (void)ws_size; (void)n_in; (void)out_size;

    float* context = (float*)d_out;                    // (N, V)
    float* att     = (float*)d_out + (long long)N * V; // (N, T)

    // Zero the context accumulator (harness poisons d_out with 0xAA).
    hipMemsetAsync(context, 0, (size_t)N * V * sizeof(float), stream);

    // K1: energy. rows = N*T, 8 rows/wave, 4 waves/block.
    {
        long long rows = (long long)N * T;
        long long waves = rows / 8;
        int blocks = (int)((waves + 3) / 4);
        energy_kernel<<<blocks, 256, 0, stream>>>(query, key, lens, att, N, T);
    }
    // K2: softmax, one block per row.
    softmax_kernel<<<N, 256, 0, stream>>>(att, T);
    // K3: context. grid (T/128, N).
    {
        dim3 grid(T / 128, N);
        context_kernel<<<grid, 256, 0, stream>>>(att, value, context, T);
    }
}

// Round 3
// 266.671 us; speedup vs baseline: 1.0592x; 1.0592x over previous
//
#include <hip/hip_runtime.h>
#include <math.h>

#define NEG_INF -1e9f

// ---------------------------------------------------------------------------
// K1: energy[n,t] = dot(key[n,t,:], query[n,:]) for t < len, else NEG_INF.
// Wave = 4 groups x 16 lanes; each group owns one row, 4 row-quads per wave
// (16 rows / wave). One __shfl_xor stage reduces all 4 rows at once ->
// 4 shuffles per 4 rows (1/row) instead of 6/row.
// Rows with t >= len: no key read at all (half the key traffic on average).
// ---------------------------------------------------------------------------
__global__ __launch_bounds__(256) void energy_kernel(
    const float* __restrict__ query,   // (N, D=256)
    const float* __restrict__ key,     // (N, T, D)
    const int*   __restrict__ lens,    // (N,)
    float*       __restrict__ energy,  // (N, T)
    int T)
{
    const int D = 256;
    const int ROWS = 16;                       // rows per wave
    const int wave = (int)((blockIdx.x * blockDim.x + threadIdx.x) >> 6);
    const int lane = threadIdx.x & 63;
    const int g    = lane >> 4;                // 0..3  (row within quad)
    const int sub  = lane & 15;                // 0..15 (16 lanes per row)
    const int wavesPerN = T / ROWS;            // 128
    const int n    = wave / wavesPerN;
    const int base = (wave % wavesPerN) * ROWS;

    const int len = lens[n];
    float* erow = energy + (long long)n * T;

    if (base >= len) {
        // Entire 16-row span is masked: store NEG_INF, read nothing.
        if (sub == 0) {
            #pragma unroll
            for (int rq = 0; rq < 4; ++rq)
                erow[base + rq * 4 + g] = NEG_INF;
        }
        return;
    }

    // Query fragments: lane needs q[sub*4 + 64*it], it = 0..3.
    const float* qn = query + (long long)n * D;
    const float4 q0 = *reinterpret_cast<const float4*>(qn + sub * 4);
    const float4 q1 = *reinterpret_cast<const float4*>(qn + sub * 4 + 64);
    const float4 q2 = *reinterpret_cast<const float4*>(qn + sub * 4 + 128);
    const float4 q3 = *reinterpret_cast<const float4*>(qn + sub * 4 + 192);

    #pragma unroll
    for (int rq = 0; rq < 4; ++rq) {
        const int row = base + rq * 4 + g;
        const bool act = row < len;
        float p = 0.f;
        if (act) {
            const float* kr = key + ((long long)n * T + row) * D + sub * 4;
            const float4 a = *reinterpret_cast<const float4*>(kr);
            const float4 b = *reinterpret_cast<const float4*>(kr + 64);
            const float4 c = *reinterpret_cast<const float4*>(kr + 128);
            const float4 d = *reinterpret_cast<const float4*>(kr + 192);
            p  = a.x*q0.x + a.y*q0.y + a.z*q0.z + a.w*q0.w;
            p += b.x*q1.x + b.y*q1.y + b.z*q1.z + b.w*q1.w;
            p += c.x*q2.x + c.y*q2.y + c.z*q2.z + c.w*q2.w;
            p += d.x*q3.x + d.y*q3.y + d.z*q3.z + d.w*q3.w;
        }
        // Reduce within each 16-lane group (all 4 rows in parallel).
        p += __shfl_xor(p, 1, 64);
        p += __shfl_xor(p, 2, 64);
        p += __shfl_xor(p, 4, 64);
        p += __shfl_xor(p, 8, 64);
        if (sub == 0)
            erow[row] = act ? p : NEG_INF;
    }
}

// ---------------------------------------------------------------------------
// K2: in-place row softmax over T=2048. One block (256 threads) per n.
// Masked entries are NEG_INF -> expf underflows to exactly 0.
// ---------------------------------------------------------------------------
__global__ __launch_bounds__(256) void softmax_kernel(
    float* __restrict__ att,  // (N, T): energy in, attention out
    int T)
{
    __shared__ float sred[256];
    const int n   = blockIdx.x;
    const int tid = threadIdx.x;
    float* row = att + (long long)n * T;

    float vals[8];
    float m = -INFINITY;
    #pragma unroll
    for (int i = 0; i < 8; ++i) {
        vals[i] = row[tid + (i << 8)];
        m = fmaxf(m, vals[i]);
    }
    sred[tid] = m;
    __syncthreads();
    #pragma unroll
    for (int s = 128; s >= 1; s >>= 1) {
        if (tid < s) sred[tid] = fmaxf(sred[tid], sred[tid + s]);
        __syncthreads();
    }
    m = sred[0];
    __syncthreads();

    float sum = 0.f;
    #pragma unroll
    for (int i = 0; i < 8; ++i) {
        vals[i] = __expf(vals[i] - m);
        sum += vals[i];
    }
    sred[tid] = sum;
    __syncthreads();
    #pragma unroll
    for (int s = 128; s >= 1; s >>= 1) {
        if (tid < s) sred[tid] += sred[tid + s];
        __syncthreads();
    }
    const float inv = 1.0f / sred[0];
    #pragma unroll
    for (int i = 0; i < 8; ++i)
        row[tid + (i << 8)] = vals[i] * inv;
}

// ---------------------------------------------------------------------------
// K3: context[n,v] += sum_t att[n,t] * value[n,t,v]. V == 256.
// Block = 256 threads (4 waves), 128-row chunk. Blocks entirely past `len`
// exit without reading; partial blocks clamp the row loop (att[t>=len]==0).
// ---------------------------------------------------------------------------
__global__ __launch_bounds__(256) void context_kernel(
    const float* __restrict__ att,     // (N, T)
    const float* __restrict__ value,   // (N, T, V)
    const int*   __restrict__ lens,    // (N,)
    float*       __restrict__ context, // (N, V), pre-zeroed
    int T)
{
    const int V = 256;
    const int CHUNK = 128;
    __shared__ float red[4][256];

    const int n   = blockIdx.y;
    const int t0  = blockIdx.x * CHUNK;
    const int len = lens[n];
    if (t0 >= len) return;                 // block-uniform early exit

    const int rows = min(len - t0, CHUNK); // 1..128
    const int wid  = threadIdx.x >> 6;     // 0..3
    const int lane = threadIdx.x & 63;
    const int v4   = lane * 4;

    const float* arow  = att + (long long)n * T + t0;
    const float* vbase = value + ((long long)n * T + t0) * V + v4;

    float4 acc = make_float4(0.f, 0.f, 0.f, 0.f);
    const int iend = min(wid * 32 + 32, rows);
    for (int i = wid * 32; i < iend; ++i) {
        const float a = arow[i];
        const float4 val = *reinterpret_cast<const float4*>(vbase + (long long)i * V);
        acc.x += a * val.x;
        acc.y += a * val.y;
        acc.z += a * val.z;
        acc.w += a * val.w;
    }
    *reinterpret_cast<float4*>(&red[wid][v4]) = acc;
    __syncthreads();

    const int v = threadIdx.x;
    const float s = red[0][v] + red[1][v] + red[2][v] + red[3][v];
    atomicAdd(context + (long long)n * V + v, s);
}

// ---------------------------------------------------------------------------
extern "C" void kernel_launch(void* const* d_in, const int* in_sizes, int n_in,
                              void* d_out, int out_size, void* d_ws, size_t ws_size,
                              hipStream_t stream) {
    const float* query = (const float*)d_in[0];
    const float* key   = (const float*)d_in[1];
    const float* value = (const float*)d_in[2];
    const int*   lens  = (const int*)d_in[3];

    const int N = in_sizes[3];                 // 64
    const int D = in_sizes[0] / N;             // 256
    const int T = in_sizes[1] / (N * D);       // 2048
    const int V = in_sizes[2] / (N * T);       // 256
    (void)D; (void)V; (void)d_ws; (void)ws_size; (void)n_in; (void)out_size;

    float* context = (float*)d_out;                    // (N, V)
    float* att     = (float*)d_out + (long long)N * V; // (N, T)

    // Zero the context accumulator (harness poisons d_out with 0xAA).
    hipMemsetAsync(context, 0, (size_t)N * V * sizeof(float), stream);

    // K1: energy. 16 rows/wave, 4 waves/block.
    {
        long long waves = (long long)N * T / 16;
        int blocks = (int)((waves + 3) / 4);
        energy_kernel<<<blocks, 256, 0, stream>>>(query, key, lens, att, T);
    }
    // K2: softmax, one block per row.
    softmax_kernel<<<N, 256, 0, stream>>>(att, T);
    // K3: context. grid (T/128, N).
    {
        dim3 grid(T / 128, N);
        context_kernel<<<grid, 256, 0, stream>>>(att, value, lens, context, T);
    }
}